// Round 1
// baseline (2879.392 us; speedup 1.0000x reference)
//
#include <hip/hip_runtime.h>
#include <cstdint>
#include <cstddef>

typedef float f32x4 __attribute__((ext_vector_type(4)));
typedef short s16x8 __attribute__((ext_vector_type(8)));
typedef unsigned short u16x4 __attribute__((ext_vector_type(4)));

#define T_LEN 256
#define B_SZ  128

__device__ __forceinline__ float bf2f(unsigned short u){
  union { unsigned int i; float f; } v; v.i = ((unsigned int)u) << 16; return v.f;
}
__device__ __forceinline__ unsigned short f2bf(float f){
  union { float f; unsigned int i; } v; v.f = f;
  return (unsigned short)((v.i + 0x7FFFu + ((v.i >> 16) & 1u)) >> 16);
}
// v_rcp_f32 (1-ulp) instead of precise-div sequence: gates are bf16-precision anyway
__device__ __forceinline__ float fast_sigmoid(float x){
  return __builtin_amdgcn_rcpf(1.0f + __builtin_amdgcn_exp2f(-1.44269504088896341f * x));
}
__device__ __forceinline__ float fast_tanh(float x){
  return 1.0f - 2.0f * __builtin_amdgcn_rcpf(1.0f + __builtin_amdgcn_exp2f(2.88539008177792681f * x));
}

// ---------------------------------------------------------------------------
// prep: cast/pad weights to bf16, build fused bias (b_ih + b_hh for r,z gates)
// ---------------------------------------------------------------------------
__global__ void prep_kernel(const float* __restrict__ w_ih0, const float* __restrict__ w_hh0,
                            const float* __restrict__ b_ih0, const float* __restrict__ b_hh0,
                            const float* __restrict__ w_ih,  const float* __restrict__ w_hh,
                            const float* __restrict__ b_ih,  const float* __restrict__ b_hh,
                            unsigned short* __restrict__ wih0b, unsigned short* __restrict__ wihb,
                            unsigned short* __restrict__ whhb,  float* __restrict__ bihc){
  const int S1 = 2*768*320;     // 491520
  const int S2 = 2*2*768*512;   // 1572864
  const int S3 = 6*768*256;     // 1179648
  const int S4 = 3*1536;        // 4608
  int idx = blockIdx.x * 256 + threadIdx.x;
  if (idx < S1){
    int k = idx % 320, r = idx / 320;              // r = dir*768 + g
    wih0b[idx] = (k < 300) ? f2bf(w_ih0[r*300 + k]) : (unsigned short)0;
  } else if (idx < S1 + S2){
    int i = idx - S1; wihb[i] = f2bf(w_ih[i]);     // layouts match flat
  } else if (idx < S1 + S2 + S3){
    int i = idx - S1 - S2;
    const int L0 = 2*768*256;
    whhb[i] = f2bf(i < L0 ? w_hh0[i] : w_hh[i - L0]);
  } else if (idx < S1 + S2 + S3 + S4){
    int i = idx - S1 - S2 - S3;
    int l = i / 1536, n = i % 1536, g = n % 768;
    float v = (l == 0) ? b_ih0[n] : b_ih[(l-1)*1536 + n];
    if (g < 512) v += (l == 0) ? b_hh0[n] : b_hh[(l-1)*1536 + n];  // fold r,z b_hh
    bihc[i] = v;
  }
}

// ---------------------------------------------------------------------------
// gather: x0[t*128+b][0:320] = bf16(emb[overview[b][t]]), zero-padded 300->320
// ---------------------------------------------------------------------------
__global__ void gather_kernel(const int* __restrict__ overview, const float* __restrict__ emb,
                              unsigned short* __restrict__ x0){
  const int m = blockIdx.x;              // t*128 + b
  const int t = m >> 7, b = m & 127;
  const int row = overview[b * T_LEN + t];
  const float* src = emb + (size_t)row * 300;
  unsigned short* dst = x0 + (size_t)m * 320;
  for (int i = threadIdx.x; i < 80; i += 64){
    u16x4 o;
    if (i < 75){
      const f32x4 v = *(const f32x4*)(src + i*4);
      o[0] = f2bf(v[0]); o[1] = f2bf(v[1]); o[2] = f2bf(v[2]); o[3] = f2bf(v[3]);
    } else { o[0] = o[1] = o[2] = o[3] = 0; }
    *(u16x4*)(dst + i*4) = o;
  }
}

// ---------------------------------------------------------------------------
// gemm_xg: xg[t][dir][b][·] = bf16( A[m]·Bw[n] + bias[n] ),  m = t*128+b, n = dir*768+g
// Output rows are chunk-XOR-swizzled: element g of row b is stored at
// ((g>>2) ^ (b&15))*4 + (g&3), so rec's linear global_load_lds image gives
// conflict-minimal LDS gate reads.
// ---------------------------------------------------------------------------
__global__ __launch_bounds__(256, 2) void gemm_xg(
    const unsigned short* __restrict__ A, const unsigned short* __restrict__ Bw,
    const float* __restrict__ bias, unsigned short* __restrict__ xg, const int K){
  __shared__ unsigned short a_t[128*40];   // +8 pad per row: conflict-free b128 reads
  __shared__ unsigned short b_t[128*40];
  const int tid = threadIdx.x;
  const int lane = tid & 63, wv = tid >> 6;
  const int l15 = lane & 15, quad = lane >> 4;
  const int m0 = blockIdx.x * 128, n0 = blockIdx.y * 128;
  const int mW = (wv >> 1) * 64, nW = (wv & 1) * 64;
  const int r0 = tid >> 2, c = (tid & 3) * 8;

  f32x4 acc[4][4];
#pragma unroll
  for (int i = 0; i < 4; ++i)
#pragma unroll
    for (int j = 0; j < 4; ++j) acc[i][j] = (f32x4){0.f,0.f,0.f,0.f};

  for (int kk = 0; kk < K; kk += 32){
    __syncthreads();
#pragma unroll
    for (int h = 0; h < 128; h += 64){
      *(s16x8*)&a_t[(r0+h)*40 + c] = *(const s16x8*)(A  + (size_t)(m0+r0+h)*K + kk + c);
      *(s16x8*)&b_t[(r0+h)*40 + c] = *(const s16x8*)(Bw + (size_t)(n0+r0+h)*K + kk + c);
    }
    __syncthreads();
    s16x8 af[4], bf[4];
#pragma unroll
    for (int i = 0; i < 4; ++i){
      af[i] = *(const s16x8*)&a_t[(mW + i*16 + l15)*40 + quad*8];
      bf[i] = *(const s16x8*)&b_t[(nW + i*16 + l15)*40 + quad*8];
    }
#pragma unroll
    for (int i = 0; i < 4; ++i)
#pragma unroll
      for (int j = 0; j < 4; ++j)
        acc[i][j] = __builtin_amdgcn_mfma_f32_16x16x32_bf16(af[i], bf[j], acc[i][j], 0, 0, 0);
  }

#pragma unroll
  for (int j = 0; j < 4; ++j){
    const int n = n0 + nW + j*16 + l15;
    const float bv = bias[n];
    const int dir = (n >= 768) ? 1 : 0;
    const int g = n - dir*768;
    const int gc = g >> 2, gl = g & 3;
#pragma unroll
    for (int i = 0; i < 4; ++i){
      const int mbase = m0 + mW + i*16 + quad*4;
#pragma unroll
      for (int r = 0; r < 4; ++r){
        const int m = mbase + r;
        const int t = m >> 7, b = m & 127;
        const int goff = ((gc ^ (b & 15)) << 2) | gl;   // row-chunk swizzle
        xg[((size_t)(t*2 + dir)*128 + b) * 768 + goff] = f2bf(acc[i][j][r] + bv);
      }
    }
  }
}

// ---------------------------------------------------------------------------
// rec_kernel: one block = one (16-batch group, direction). 4 waves, 256 steps.
// Restructured: ONE raw s_barrier per step (h double-buffered in LDS),
// xg staged via global_load_lds DMA with a full-step latency window
// (fence = counted vmcnt(4): the 4 newest VMEM ops are this step's y-stores),
// 10 W-tiles in registers + 2 in LDS, n-gate b_hh hoisted.
// grid = 16: blockIdx = bg(0..7) | dir<<3
// ---------------------------------------------------------------------------
__global__ __launch_bounds__(256, 1) void rec_kernel(
    const unsigned short* __restrict__ xg,   // [T][2][128][768] bf16 (chunk-swizzled rows)
    const unsigned short* __restrict__ whh2, // [2][768][256] bf16 (this layer)
    const float* __restrict__ bhh2,          // [2][768] f32 (this layer)
    unsigned short* __restrict__ y){         // [T][128][512] bf16
  extern __shared__ unsigned short sm[];
  unsigned short* w_lds  = sm;                      // [4][2][16][264]
  unsigned short* h_lds  = sm + 4*2*16*264;         // [2][16][264] double-buffered
  unsigned short* xg_lds = h_lds + 2*16*264;        // [2][16][768] linear (DMA target)

  const int tid  = threadIdx.x;
  const int lane = tid & 63;
  const int wv   = tid >> 6;
  const int l15  = lane & 15;
  const int quad = lane >> 4;
  const int bg   = blockIdx.x & 7;
  const int dir  = blockIdx.x >> 3;
  const int bgBase = bg * 16;

  const unsigned short* whh = whh2 + dir * (768*256);

  // n-gate b_hh: loop-invariant -> hoist into registers
  f32x4 bn[4];
#pragma unroll
  for (int jt = 0; jt < 4; ++jt)
    bn[jt] = *(const f32x4*)(bhh2 + dir*768 + 512 + wv*64 + jt*16 + quad*4);

  for (int i = tid; i < 16*264; i += 256) h_lds[i] = 0;   // zero h buffer 0

  // A(weight) fragments, tiles i=0..9 in registers (gt=i>>2: 0=r,1=z,2=n; jt=i&3)
  s16x8 wreg[10][8];
#pragma unroll
  for (int i = 0; i < 10; ++i){
    const int gt = i >> 2, jt = i & 3;
    const unsigned short* src = whh + (size_t)(gt*256 + wv*64 + jt*16 + l15) * 256;
#pragma unroll
    for (int ks = 0; ks < 8; ++ks)
      wreg[i][ks] = *(const s16x8*)(src + ks*32 + quad*8);
  }
  // tiles i=10,11 (gt=2, jt=2,3) staged once into LDS
#pragma unroll
  for (int ti = 0; ti < 2; ++ti){
    const int i = 10 + ti, gt = i >> 2, jt = i & 3;
    const int row = lane >> 2;
    const int col = (lane & 3) * 64;
    const unsigned short* src = whh + (size_t)(gt*256 + wv*64 + jt*16 + row) * 256 + col;
    unsigned short* dst = w_lds + ((wv*2 + ti)*16 + row) * 264 + col;
#pragma unroll
    for (int c8 = 0; c8 < 8; ++c8)
      *(s16x8*)(dst + c8*8) = *(const s16x8*)(src + c8*8);
  }

  float hreg[16];
#pragma unroll
  for (int i = 0; i < 16; ++i) hreg[i] = 0.0f;

  // DMA one step's 16x768 bf16 slab (24 KB) linearly into LDS buffer `buf`.
  // Wave wv copies chunks k = wv*6 .. wv*6+5 (1024 B each, lane*16 within).
  auto stage = [&](int t, int buf){
    const char* g = (const char*)(xg + ((size_t)(t*2 + dir)*128 + bgBase) * 768);
    char* l = (char*)(xg_lds + buf * (16*768));
#pragma unroll
    for (int j = 0; j < 6; ++j){
      const int k = wv*6 + j;
      __builtin_amdgcn_global_load_lds(
          (const __attribute__((address_space(1))) unsigned int*)(g + k*1024 + (size_t)lane*16),
          (__attribute__((address_space(3))) unsigned int*)(l + k*1024), 16, 0, 0);
    }
  };

  stage(dir ? (T_LEN - 1) : 0, 0);
  asm volatile("s_waitcnt vmcnt(0) lgkmcnt(0)" ::: "memory");
  __builtin_amdgcn_s_barrier();
  __builtin_amdgcn_sched_barrier(0);

  for (int s = 0; s < T_LEN; ++s){
    const int cur = s & 1;
    const int t = dir ? (T_LEN - 1 - s) : s;

    // (a) issue next-step DMA early: latency window = the entire step
    if (s + 1 < T_LEN) stage(dir ? (T_LEN - 2 - s) : (s + 1), cur ^ 1);
    __builtin_amdgcn_sched_barrier(0);   // pin DMA issue before MFMA/stores

    // (b) hg = W·h : B-frags from h_lds[cur]
    s16x8 bfr[8];
    const unsigned short* hbase = h_lds + cur*(16*264) + l15*264;
#pragma unroll
    for (int ks = 0; ks < 8; ++ks)
      bfr[ks] = *(const s16x8*)(hbase + ks*32 + quad*8);

    f32x4 acc[12];
#pragma unroll
    for (int i = 0; i < 12; ++i) acc[i] = (f32x4){0.f,0.f,0.f,0.f};
#pragma unroll
    for (int i = 0; i < 10; ++i)
#pragma unroll
      for (int ks = 0; ks < 8; ++ks)
        acc[i] = __builtin_amdgcn_mfma_f32_16x16x32_bf16(wreg[i][ks], bfr[ks], acc[i], 0, 0, 0);
#pragma unroll
    for (int ti = 0; ti < 2; ++ti)
#pragma unroll
      for (int ks = 0; ks < 8; ++ks){
        s16x8 af = *(const s16x8*)(w_lds + ((wv*2 + ti)*16 + l15)*264 + ks*32 + quad*8);
        acc[10+ti] = __builtin_amdgcn_mfma_f32_16x16x32_bf16(af, bfr[ks], acc[10+ti], 0, 0, 0);
      }

    // (e) gates: lane holds (b=l15, j=wv*64+jt*16+quad*4+r); xg reads de-swizzle
    const unsigned short* curx = xg_lds + cur*(16*768) + l15*768;
    unsigned short* hwb = h_lds + (cur^1)*(16*264) + l15*264;
#pragma unroll
    for (int jt = 0; jt < 4; ++jt){
      const int off0 = (wv*16 + ((jt*4 + quad) ^ l15)) * 4;   // chunk ^ (b&15)
      u16x4 xr4 = *(const u16x4*)(curx + off0);
      u16x4 xz4 = *(const u16x4*)(curx + off0 + 256);
      u16x4 xn4 = *(const u16x4*)(curx + off0 + 512);
      f32x4 ra = acc[jt], za = acc[4+jt], na = acc[8+jt];
      u16x4 hw;
#pragma unroll
      for (int r = 0; r < 4; ++r){
        float rr = fast_sigmoid(bf2f(xr4[r]) + ra[r]);
        float zz = fast_sigmoid(bf2f(xz4[r]) + za[r]);
        float nn = fast_tanh(bf2f(xn4[r]) + rr * (na[r] + bn[jt][r]));
        float hv = nn + zz * (hreg[jt*4 + r] - nn);
        hreg[jt*4 + r] = hv;
        hw[r] = f2bf(hv);
      }
      *(u16x4*)(hwb + wv*64 + jt*16 + quad*4) = hw;
      *(u16x4*)(y + ((size_t)t*128 + bgBase + l15) * 512 + dir*256 + wv*64 + jt*16 + quad*4) = hw;
    }

    // fence: 4 newest VMEM ops are this step's y-stores; everything older
    // (incl. the 6 DMA loads for step s+1) must be complete. lgkmcnt(0) makes
    // the h_lds/xg LDS ops visible across the barrier.
    asm volatile("s_waitcnt vmcnt(4) lgkmcnt(0)" ::: "memory");
    __builtin_amdgcn_s_barrier();
    __builtin_amdgcn_sched_barrier(0);
  }
}

// ---------------------------------------------------------------------------
// final: out[b][o] = sum_j y[T-1][b][j] * lin_w[o][j] + lin_b[o]
// ---------------------------------------------------------------------------
__global__ void final_kernel(const unsigned short* __restrict__ y, const float* __restrict__ lin_w,
                             const float* __restrict__ lin_b, float* __restrict__ out){
  const int b = blockIdx.x, lane = threadIdx.x;  // 64 threads
  s16x8 hv = *(const s16x8*)(y + ((size_t)((T_LEN-1)*128 + b)) * 512 + lane*8);
  float hf[8];
#pragma unroll
  for (int i = 0; i < 8; ++i) hf[i] = bf2f((unsigned short)hv[i]);
  float p[18];
#pragma unroll
  for (int o = 0; o < 18; ++o) p[o] = 0.0f;
#pragma unroll
  for (int i = 0; i < 8; ++i)
#pragma unroll
    for (int o = 0; o < 18; ++o) p[o] += hf[i] * lin_w[o*512 + lane*8 + i];
#pragma unroll
  for (int o = 0; o < 18; ++o){
    float v = p[o];
    for (int off = 32; off > 0; off >>= 1) v += __shfl_xor(v, off, 64);
    if (lane == 0) out[b*18 + o] = v + lin_b[o];
  }
}

// ---------------------------------------------------------------------------
extern "C" void kernel_launch(void* const* d_in, const int* in_sizes, int n_in,
                              void* d_out, int out_size, void* d_ws, size_t ws_size,
                              hipStream_t stream){
  const int*   overview = (const int*)  d_in[0];
  const float* emb   = (const float*)d_in[1];
  const float* w_ih0 = (const float*)d_in[2];
  const float* w_hh0 = (const float*)d_in[3];
  const float* b_ih0 = (const float*)d_in[4];
  const float* b_hh0 = (const float*)d_in[5];
  const float* w_ih  = (const float*)d_in[6];
  const float* w_hh  = (const float*)d_in[7];
  const float* b_ih  = (const float*)d_in[8];
  const float* b_hh  = (const float*)d_in[9];
  const float* lin_w = (const float*)d_in[10];
  const float* lin_b = (const float*)d_in[11];
  float* out = (float*)d_out;

  char* ws = (char*)d_ws;
  size_t off = 0;
  auto alloc = [&](size_t bytes) -> char* {
    char* p = ws + off; off += (bytes + 511) & ~(size_t)511; return p;
  };
  unsigned short* x0    = (unsigned short*)alloc((size_t)32768*320*2);
  unsigned short* wih0b = (unsigned short*)alloc((size_t)2*768*320*2);
  unsigned short* wihb  = (unsigned short*)alloc((size_t)2*2*768*512*2);
  unsigned short* whhb  = (unsigned short*)alloc((size_t)6*768*256*2);
  float*          bihc  = (float*)         alloc((size_t)3*1536*4);
  unsigned short* xgb   = (unsigned short*)alloc((size_t)256*2*128*768*2);
  unsigned short* ya    = (unsigned short*)alloc((size_t)32768*512*2);
  unsigned short* yb    = (unsigned short*)alloc((size_t)32768*512*2);

  const size_t REC_LDS = (size_t)(4*2*16*264 + 2*16*264 + 2*16*768) * 2;  // 133632 B
  hipFuncSetAttribute((const void*)rec_kernel,
                      hipFuncAttributeMaxDynamicSharedMemorySize, (int)REC_LDS);

  prep_kernel<<<dim3(12690), 256, 0, stream>>>(w_ih0, w_hh0, b_ih0, b_hh0,
                                               w_ih, w_hh, b_ih, b_hh,
                                               wih0b, wihb, whhb, bihc);
  gather_kernel<<<dim3(32768), 64, 0, stream>>>(overview, emb, x0);

  // layer 0
  gemm_xg<<<dim3(256, 12), 256, 0, stream>>>(x0, wih0b, bihc, xgb, 320);
  rec_kernel<<<dim3(16), 256, REC_LDS, stream>>>(xgb, whhb, b_hh0, ya);
  // layer 1
  gemm_xg<<<dim3(256, 12), 256, 0, stream>>>(ya, wihb, bihc + 1536, xgb, 512);
  rec_kernel<<<dim3(16), 256, REC_LDS, stream>>>(xgb, whhb + 2*768*256, b_hh, yb);
  // layer 2
  gemm_xg<<<dim3(256, 12), 256, 0, stream>>>(yb, wihb + (size_t)2*768*512, bihc + 2*1536, xgb, 512);
  rec_kernel<<<dim3(16), 256, REC_LDS, stream>>>(xgb, whhb + 4*768*256, b_hh + 1536, ya);

  final_kernel<<<dim3(128), 64, 0, stream>>>(ya, lin_w, lin_b, out);
}

// Round 2
// 2806.638 us; speedup vs baseline: 1.0259x; 1.0259x over previous
//
#include <hip/hip_runtime.h>
#include <cstdint>
#include <cstddef>

typedef float f32x4 __attribute__((ext_vector_type(4)));
typedef short s16x8 __attribute__((ext_vector_type(8)));
typedef unsigned short u16x4 __attribute__((ext_vector_type(4)));

#define T_LEN 256
#define B_SZ  128

__device__ __forceinline__ float bf2f(unsigned short u){
  union { unsigned int i; float f; } v; v.i = ((unsigned int)u) << 16; return v.f;
}
__device__ __forceinline__ unsigned short f2bf(float f){
  union { float f; unsigned int i; } v; v.f = f;
  return (unsigned short)((v.i + 0x7FFFu + ((v.i >> 16) & 1u)) >> 16);
}
// v_rcp_f32 (1-ulp) instead of precise-div sequence: gates are bf16-precision anyway
__device__ __forceinline__ float fast_sigmoid(float x){
  return __builtin_amdgcn_rcpf(1.0f + __builtin_amdgcn_exp2f(-1.44269504088896341f * x));
}
__device__ __forceinline__ float fast_tanh(float x){
  return 1.0f - 2.0f * __builtin_amdgcn_rcpf(1.0f + __builtin_amdgcn_exp2f(2.88539008177792681f * x));
}

// ---------------------------------------------------------------------------
// prep: cast/pad weights to bf16, build fused bias (b_ih + b_hh for r,z gates)
// ---------------------------------------------------------------------------
__global__ void prep_kernel(const float* __restrict__ w_ih0, const float* __restrict__ w_hh0,
                            const float* __restrict__ b_ih0, const float* __restrict__ b_hh0,
                            const float* __restrict__ w_ih,  const float* __restrict__ w_hh,
                            const float* __restrict__ b_ih,  const float* __restrict__ b_hh,
                            unsigned short* __restrict__ wih0b, unsigned short* __restrict__ wihb,
                            unsigned short* __restrict__ whhb,  float* __restrict__ bihc){
  const int S1 = 2*768*320;     // 491520
  const int S2 = 2*2*768*512;   // 1572864
  const int S3 = 6*768*256;     // 1179648
  const int S4 = 3*1536;        // 4608
  int idx = blockIdx.x * 256 + threadIdx.x;
  if (idx < S1){
    int k = idx % 320, r = idx / 320;              // r = dir*768 + g
    wih0b[idx] = (k < 300) ? f2bf(w_ih0[r*300 + k]) : (unsigned short)0;
  } else if (idx < S1 + S2){
    int i = idx - S1; wihb[i] = f2bf(w_ih[i]);     // layouts match flat
  } else if (idx < S1 + S2 + S3){
    int i = idx - S1 - S2;
    const int L0 = 2*768*256;
    whhb[i] = f2bf(i < L0 ? w_hh0[i] : w_hh[i - L0]);
  } else if (idx < S1 + S2 + S3 + S4){
    int i = idx - S1 - S2 - S3;
    int l = i / 1536, n = i % 1536, g = n % 768;
    float v = (l == 0) ? b_ih0[n] : b_ih[(l-1)*1536 + n];
    if (g < 512) v += (l == 0) ? b_hh0[n] : b_hh[(l-1)*1536 + n];  // fold r,z b_hh
    bihc[i] = v;
  }
}

// ---------------------------------------------------------------------------
// gather: x0[t*128+b][0:320] = bf16(emb[overview[b][t]]), zero-padded 300->320
// ---------------------------------------------------------------------------
__global__ void gather_kernel(const int* __restrict__ overview, const float* __restrict__ emb,
                              unsigned short* __restrict__ x0){
  const int m = blockIdx.x;              // t*128 + b
  const int t = m >> 7, b = m & 127;
  const int row = overview[b * T_LEN + t];
  const float* src = emb + (size_t)row * 300;
  unsigned short* dst = x0 + (size_t)m * 320;
  for (int i = threadIdx.x; i < 80; i += 64){
    u16x4 o;
    if (i < 75){
      const f32x4 v = *(const f32x4*)(src + i*4);
      o[0] = f2bf(v[0]); o[1] = f2bf(v[1]); o[2] = f2bf(v[2]); o[3] = f2bf(v[3]);
    } else { o[0] = o[1] = o[2] = o[3] = 0; }
    *(u16x4*)(dst + i*4) = o;
  }
}

// ---------------------------------------------------------------------------
// gemm_xg: xg[t][dir][b][·] = bf16( A[m]·Bw[n] + bias[n] ),  m = t*128+b, n = dir*768+g
// Output rows are chunk-XOR-swizzled: element g of row b is stored at
// ((g>>2) ^ (b&15))*4 + (g&3), so rec's linear global_load_lds image gives
// conflict-minimal LDS gate reads.
// ---------------------------------------------------------------------------
__global__ __launch_bounds__(256, 2) void gemm_xg(
    const unsigned short* __restrict__ A, const unsigned short* __restrict__ Bw,
    const float* __restrict__ bias, unsigned short* __restrict__ xg, const int K){
  __shared__ unsigned short a_t[128*40];   // +8 pad per row: conflict-free b128 reads
  __shared__ unsigned short b_t[128*40];
  const int tid = threadIdx.x;
  const int lane = tid & 63, wv = tid >> 6;
  const int l15 = lane & 15, quad = lane >> 4;
  const int m0 = blockIdx.x * 128, n0 = blockIdx.y * 128;
  const int mW = (wv >> 1) * 64, nW = (wv & 1) * 64;
  const int r0 = tid >> 2, c = (tid & 3) * 8;

  f32x4 acc[4][4];
#pragma unroll
  for (int i = 0; i < 4; ++i)
#pragma unroll
    for (int j = 0; j < 4; ++j) acc[i][j] = (f32x4){0.f,0.f,0.f,0.f};

  for (int kk = 0; kk < K; kk += 32){
    __syncthreads();
#pragma unroll
    for (int h = 0; h < 128; h += 64){
      *(s16x8*)&a_t[(r0+h)*40 + c] = *(const s16x8*)(A  + (size_t)(m0+r0+h)*K + kk + c);
      *(s16x8*)&b_t[(r0+h)*40 + c] = *(const s16x8*)(Bw + (size_t)(n0+r0+h)*K + kk + c);
    }
    __syncthreads();
    s16x8 af[4], bf[4];
#pragma unroll
    for (int i = 0; i < 4; ++i){
      af[i] = *(const s16x8*)&a_t[(mW + i*16 + l15)*40 + quad*8];
      bf[i] = *(const s16x8*)&b_t[(nW + i*16 + l15)*40 + quad*8];
    }
#pragma unroll
    for (int i = 0; i < 4; ++i)
#pragma unroll
      for (int j = 0; j < 4; ++j)
        acc[i][j] = __builtin_amdgcn_mfma_f32_16x16x32_bf16(af[i], bf[j], acc[i][j], 0, 0, 0);
  }

#pragma unroll
  for (int j = 0; j < 4; ++j){
    const int n = n0 + nW + j*16 + l15;
    const float bv = bias[n];
    const int dir = (n >= 768) ? 1 : 0;
    const int g = n - dir*768;
    const int gc = g >> 2, gl = g & 3;
#pragma unroll
    for (int i = 0; i < 4; ++i){
      const int mbase = m0 + mW + i*16 + quad*4;
#pragma unroll
      for (int r = 0; r < 4; ++r){
        const int m = mbase + r;
        const int t = m >> 7, b = m & 127;
        const int goff = ((gc ^ (b & 15)) << 2) | gl;   // row-chunk swizzle
        xg[((size_t)(t*2 + dir)*128 + b) * 768 + goff] = f2bf(acc[i][j][r] + bv);
      }
    }
  }
}

// ---------------------------------------------------------------------------
// rec_kernel: one block = one (16-batch group, direction). 4 waves, 256 steps.
// This revision targets register-spill elimination + DMA latency:
//  - ks-outer MFMA loop: only ONE h B-fragment live at a time (-24 VGPR)
//  - running pointers for y-store / xg-stage (no per-step 64-bit addr rebuild)
//  - xg triple-buffered (prefetch distance 2), counted fence vmcnt(10)
// grid = 16: blockIdx = bg(0..7) | dir<<3
// ---------------------------------------------------------------------------
__global__ __launch_bounds__(256, 1) void rec_kernel(
    const unsigned short* __restrict__ xg,   // [T][2][128][768] bf16 (chunk-swizzled rows)
    const unsigned short* __restrict__ whh2, // [2][768][256] bf16 (this layer)
    const float* __restrict__ bhh2,          // [2][768] f32 (this layer)
    unsigned short* __restrict__ y){         // [T][128][512] bf16
  extern __shared__ unsigned short sm[];
  unsigned short* w_lds  = sm;                      // [4][2][16][264]
  unsigned short* h_lds  = sm + 4*2*16*264;         // [2][16][264] double-buffered
  unsigned short* xg_lds = h_lds + 2*16*264;        // [3][16][768] linear (DMA target)

  const int tid  = threadIdx.x;
  const int lane = tid & 63;
  const int wv   = tid >> 6;
  const int l15  = lane & 15;
  const int quad = lane >> 4;
  const int bg   = blockIdx.x & 7;
  const int dir  = blockIdx.x >> 3;
  const int bgBase = bg * 16;

  const unsigned short* whh = whh2 + dir * (768*256);

  // n-gate b_hh: loop-invariant -> registers
  f32x4 bn[4];
#pragma unroll
  for (int jt = 0; jt < 4; ++jt)
    bn[jt] = *(const f32x4*)(bhh2 + dir*768 + 512 + wv*64 + jt*16 + quad*4);

  for (int i = tid; i < 16*264; i += 256) h_lds[i] = 0;   // zero h buffer 0

  // A(weight) fragments, tiles i=0..9 in registers (gt=i>>2: 0=r,1=z,2=n; jt=i&3)
  s16x8 wreg[10][8];
#pragma unroll
  for (int i = 0; i < 10; ++i){
    const int gt = i >> 2, jt = i & 3;
    const unsigned short* src = whh + (size_t)(gt*256 + wv*64 + jt*16 + l15) * 256;
#pragma unroll
    for (int ks = 0; ks < 8; ++ks)
      wreg[i][ks] = *(const s16x8*)(src + ks*32 + quad*8);
  }
  // tiles i=10,11 (gt=2, jt=2,3) staged once into LDS
#pragma unroll
  for (int ti = 0; ti < 2; ++ti){
    const int i = 10 + ti, gt = i >> 2, jt = i & 3;
    const int row = lane >> 2;
    const int col = (lane & 3) * 64;
    const unsigned short* src = whh + (size_t)(gt*256 + wv*64 + jt*16 + row) * 256 + col;
    unsigned short* dst = w_lds + ((wv*2 + ti)*16 + row) * 264 + col;
#pragma unroll
    for (int c8 = 0; c8 < 8; ++c8)
      *(s16x8*)(dst + c8*8) = *(const s16x8*)(src + c8*8);
  }

  float hreg[16];
#pragma unroll
  for (int i = 0; i < 16; ++i) hreg[i] = 0.0f;

  // DMA one step's 16x768 bf16 slab (24 KB) linearly into LDS buffer `buf`.
  // Wave wv copies chunks k = wv*6 .. wv*6+5 (1024 B each, lane*16 within).
  auto stage = [&](const unsigned short* src_base, int buf){
    const char* g = (const char*)src_base;
    char* l = (char*)(xg_lds + buf * (16*768));
#pragma unroll
    for (int j = 0; j < 6; ++j){
      const int k = wv*6 + j;
      __builtin_amdgcn_global_load_lds(
          (const __attribute__((address_space(1))) unsigned int*)(g + k*1024 + (size_t)lane*16),
          (__attribute__((address_space(3))) unsigned int*)(l + k*1024), 16, 0, 0);
    }
  };

  // running pointers (avoid per-step 64-bit address rebuild)
  const int t0 = dir ? (T_LEN - 1) : 0;
  const ptrdiff_t step_x = dir ? -(ptrdiff_t)(2*128*768) : (ptrdiff_t)(2*128*768);
  const ptrdiff_t step_y = dir ? -(ptrdiff_t)(128*512)   : (ptrdiff_t)(128*512);
  const unsigned short* xg0 = xg + ((size_t)(t0*2 + dir)*128 + bgBase) * 768;
  unsigned short* yptr = y + ((size_t)t0*128 + bgBase + l15) * 512 + dir*256 + wv*64 + quad*4;

  // prologue: prefetch steps 0 and 1
  stage(xg0, 0);
  stage(xg0 + step_x, 1);
  const unsigned short* sptr = xg0 + 2*step_x;   // source for step 2

  asm volatile("s_waitcnt vmcnt(6) lgkmcnt(0)" ::: "memory");  // step-0 slab + LDS init done
  __builtin_amdgcn_s_barrier();
  __builtin_amdgcn_sched_barrier(0);

  int c3 = 0;     // buffer of step s
  int b3 = 2;     // buffer of step s+2
  for (int s = 0; s < T_LEN; ++s){
    const int cur2 = s & 1;

    // (a) issue step-(s+2) DMA: latency window = two full steps
    if (s + 2 < T_LEN){
      stage(sptr, b3);
      sptr += step_x;
    }
    __builtin_amdgcn_sched_barrier(0);   // pin DMA issue before MFMA

    // (b) hg = W·h, ks-outer: one B-fragment live at a time
    const unsigned short* hbase = h_lds + cur2*(16*264) + l15*264;
    f32x4 acc[12];
#pragma unroll
    for (int i = 0; i < 12; ++i) acc[i] = (f32x4){0.f,0.f,0.f,0.f};
#pragma unroll
    for (int ks = 0; ks < 8; ++ks){
      const s16x8 bfr = *(const s16x8*)(hbase + ks*32 + quad*8);
#pragma unroll
      for (int i = 0; i < 10; ++i)
        acc[i] = __builtin_amdgcn_mfma_f32_16x16x32_bf16(wreg[i][ks], bfr, acc[i], 0, 0, 0);
#pragma unroll
      for (int ti = 0; ti < 2; ++ti){
        s16x8 af = *(const s16x8*)(w_lds + ((wv*2 + ti)*16 + l15)*264 + ks*32 + quad*8);
        acc[10+ti] = __builtin_amdgcn_mfma_f32_16x16x32_bf16(af, bfr, acc[10+ti], 0, 0, 0);
      }
    }

    // (e) gates: lane holds (b=l15, j=wv*64+jt*16+quad*4+r); xg reads de-swizzle
    const unsigned short* curx = xg_lds + c3*(16*768) + l15*768;
    unsigned short* hwb = h_lds + (cur2^1)*(16*264) + l15*264;
#pragma unroll
    for (int jt = 0; jt < 4; ++jt){
      const int off0 = (wv*16 + ((jt*4 + quad) ^ l15)) * 4;   // chunk ^ (b&15)
      u16x4 xr4 = *(const u16x4*)(curx + off0);
      u16x4 xz4 = *(const u16x4*)(curx + off0 + 256);
      u16x4 xn4 = *(const u16x4*)(curx + off0 + 512);
      f32x4 ra = acc[jt], za = acc[4+jt], na = acc[8+jt];
      u16x4 hw;
#pragma unroll
      for (int r = 0; r < 4; ++r){
        float rr = fast_sigmoid(bf2f(xr4[r]) + ra[r]);
        float zz = fast_sigmoid(bf2f(xz4[r]) + za[r]);
        float nn = fast_tanh(bf2f(xn4[r]) + rr * (na[r] + bn[jt][r]));
        float hv = nn + zz * (hreg[jt*4 + r] - nn);
        hreg[jt*4 + r] = hv;
        hw[r] = f2bf(hv);
      }
      *(u16x4*)(hwb + wv*64 + jt*16 + quad*4) = hw;
      *(u16x4*)(yptr + jt*16) = hw;
    }
    yptr += step_y;
    c3 = (c3 == 2) ? 0 : (c3 + 1);
    b3 = (b3 == 2) ? 0 : (b3 + 1);

    // fence: newest outstanding VMEM = 6 DMA(s+2) + 4 y-stores(s) = 10.
    // Waiting to <=10 forces DMA(s+1) + stores(s-1) complete. Tail: vmcnt(4).
    if (s + 2 < T_LEN) asm volatile("s_waitcnt vmcnt(10) lgkmcnt(0)" ::: "memory");
    else               asm volatile("s_waitcnt vmcnt(4) lgkmcnt(0)"  ::: "memory");
    __builtin_amdgcn_s_barrier();
    __builtin_amdgcn_sched_barrier(0);
  }
}

// ---------------------------------------------------------------------------
// final: out[b][o] = sum_j y[T-1][b][j] * lin_w[o][j] + lin_b[o]
// ---------------------------------------------------------------------------
__global__ void final_kernel(const unsigned short* __restrict__ y, const float* __restrict__ lin_w,
                             const float* __restrict__ lin_b, float* __restrict__ out){
  const int b = blockIdx.x, lane = threadIdx.x;  // 64 threads
  s16x8 hv = *(const s16x8*)(y + ((size_t)((T_LEN-1)*128 + b)) * 512 + lane*8);
  float hf[8];
#pragma unroll
  for (int i = 0; i < 8; ++i) hf[i] = bf2f((unsigned short)hv[i]);
  float p[18];
#pragma unroll
  for (int o = 0; o < 18; ++o) p[o] = 0.0f;
#pragma unroll
  for (int i = 0; i < 8; ++i)
#pragma unroll
    for (int o = 0; o < 18; ++o) p[o] += hf[i] * lin_w[o*512 + lane*8 + i];
#pragma unroll
  for (int o = 0; o < 18; ++o){
    float v = p[o];
    for (int off = 32; off > 0; off >>= 1) v += __shfl_xor(v, off, 64);
    if (lane == 0) out[b*18 + o] = v + lin_b[o];
  }
}

// ---------------------------------------------------------------------------
extern "C" void kernel_launch(void* const* d_in, const int* in_sizes, int n_in,
                              void* d_out, int out_size, void* d_ws, size_t ws_size,
                              hipStream_t stream){
  const int*   overview = (const int*)  d_in[0];
  const float* emb   = (const float*)d_in[1];
  const float* w_ih0 = (const float*)d_in[2];
  const float* w_hh0 = (const float*)d_in[3];
  const float* b_ih0 = (const float*)d_in[4];
  const float* b_hh0 = (const float*)d_in[5];
  const float* w_ih  = (const float*)d_in[6];
  const float* w_hh  = (const float*)d_in[7];
  const float* b_ih  = (const float*)d_in[8];
  const float* b_hh  = (const float*)d_in[9];
  const float* lin_w = (const float*)d_in[10];
  const float* lin_b = (const float*)d_in[11];
  float* out = (float*)d_out;

  char* ws = (char*)d_ws;
  size_t off = 0;
  auto alloc = [&](size_t bytes) -> char* {
    char* p = ws + off; off += (bytes + 511) & ~(size_t)511; return p;
  };
  unsigned short* x0    = (unsigned short*)alloc((size_t)32768*320*2);
  unsigned short* wih0b = (unsigned short*)alloc((size_t)2*768*320*2);
  unsigned short* wihb  = (unsigned short*)alloc((size_t)2*2*768*512*2);
  unsigned short* whhb  = (unsigned short*)alloc((size_t)6*768*256*2);
  float*          bihc  = (float*)         alloc((size_t)3*1536*4);
  unsigned short* xgb   = (unsigned short*)alloc((size_t)256*2*128*768*2);
  unsigned short* ya    = (unsigned short*)alloc((size_t)32768*512*2);
  unsigned short* yb    = (unsigned short*)alloc((size_t)32768*512*2);

  const size_t REC_LDS = (size_t)(4*2*16*264 + 2*16*264 + 3*16*768) * 2;  // 158208 B
  hipFuncSetAttribute((const void*)rec_kernel,
                      hipFuncAttributeMaxDynamicSharedMemorySize, (int)REC_LDS);

  prep_kernel<<<dim3(12690), 256, 0, stream>>>(w_ih0, w_hh0, b_ih0, b_hh0,
                                               w_ih, w_hh, b_ih, b_hh,
                                               wih0b, wihb, whhb, bihc);
  gather_kernel<<<dim3(32768), 64, 0, stream>>>(overview, emb, x0);

  // layer 0
  gemm_xg<<<dim3(256, 12), 256, 0, stream>>>(x0, wih0b, bihc, xgb, 320);
  rec_kernel<<<dim3(16), 256, REC_LDS, stream>>>(xgb, whhb, b_hh0, ya);
  // layer 1
  gemm_xg<<<dim3(256, 12), 256, 0, stream>>>(ya, wihb, bihc + 1536, xgb, 512);
  rec_kernel<<<dim3(16), 256, REC_LDS, stream>>>(xgb, whhb + 2*768*256, b_hh, yb);
  // layer 2
  gemm_xg<<<dim3(256, 12), 256, 0, stream>>>(yb, wihb + (size_t)2*768*512, bihc + 2*1536, xgb, 512);
  rec_kernel<<<dim3(16), 256, REC_LDS, stream>>>(xgb, whhb + 4*768*256, b_hh + 1536, ya);

  final_kernel<<<dim3(128), 64, 0, stream>>>(ya, lin_w, lin_b, out);
}